// Round 1
// baseline (392.365 us; speedup 1.0000x reference)
//
#include <hip/hip_runtime.h>

// MHSA: X(1,2048,2048) fp32; W_Q/K/V(16,2048,128); W_out(2048,2048); out (2048,2048) fp32.
// Pipeline: cvt X -> bf16; transpose-cvt W -> bf16 (B^T layout for K-contiguous frags);
// fused QKV GEMM (bf16 MFMA, Q pre-scaled by 1/sqrt(128), V written transposed);
// flash attention (online softmax); out-proj GEMM (fp32 out).
// Workspace layout (needs 64 MiB):
//   Xb    @ 0        (8 MiB)  X as bf16
//   Wqkvb @ 8 MiB    (24 MiB) W_Q^T|W_K^T|W_V^T per head (n,h,d) bf16
//   Woutb @ 32 MiB   (8 MiB)  W_out^T (n,k) bf16
//   Qb    @ 40 MiB   (8 MiB)  (n,t,h) bf16, pre-scaled
//   Kb    @ 48 MiB   (8 MiB)  (n,t,h) bf16
//   VTb   @ 56 MiB   (8 MiB)  (n,h,t) bf16  (transposed for PV B-operand)
//   Rb    @ 8 MiB    (aliases dead Wqkvb[Q] region) (t, n*h) bf16

typedef unsigned short u16;
typedef __bf16 bf16x8 __attribute__((ext_vector_type(8)));
typedef float f32x4 __attribute__((ext_vector_type(4)));
typedef __attribute__((address_space(1))) void gvoid;
typedef __attribute__((address_space(3))) void svoid;

union B8 { uint4 u; bf16x8 b; };

__device__ __forceinline__ u16 f2b(float f) {
  unsigned int u = __float_as_uint(f);
  unsigned int r = (u + 0x7FFFu + ((u >> 16) & 1u)) >> 16;  // RNE
  return (u16)r;
}

// ---------------- convert X: fp32 -> bf16, 4 elems/thread ----------------
__global__ __launch_bounds__(256) void cvt_x_kernel(const float* __restrict__ x,
                                                    u16* __restrict__ xb) {
  int i = (blockIdx.x * 256 + threadIdx.x) * 4;
  float4 v = *(const float4*)(x + i);
  ushort4 o;
  o.x = f2b(v.x); o.y = f2b(v.y); o.z = f2b(v.z); o.w = f2b(v.w);
  *(ushort4*)(xb + i) = o;
}

// ------- transpose+convert: src (batch,K,N) f32 -> dst (batch,N,K) bf16 -------
__global__ __launch_bounds__(256) void tcvt_kernel(const float* __restrict__ src,
                                                   u16* __restrict__ dst, int K, int N) {
  __shared__ float t[32][33];
  int bz = blockIdx.z;
  int n0 = blockIdx.x * 32, k0 = blockIdx.y * 32;
  const float* S = src + (size_t)bz * K * N;
  u16* D = dst + (size_t)bz * K * N;
  int tx = threadIdx.x, ty = threadIdx.y;  // (32,8)
#pragma unroll
  for (int d = 0; d < 4; ++d)
    t[ty + d * 8][tx] = S[(size_t)(k0 + ty + d * 8) * N + n0 + tx];
  __syncthreads();
#pragma unroll
  for (int d = 0; d < 4; ++d)
    D[(size_t)(n0 + ty + d * 8) * K + k0 + tx] = f2b(t[tx][ty + d * 8]);
}

// ---------------- shared GEMM mainloop: C(128x128) = A(128x2048) * B^T(128x2048)^T --------
// A,B panels row-major stride 2048 bf16. LDS tiles [128][64] bf16, XOR-swizzled
// (byte ^= ((byte>>7)&7)<<4) so ds_read_b128 column-slices are 2-way (free).
// global_load_lds writes linearly -> source addresses are pre-inverse-swizzled (m173/m201).
__device__ __forceinline__ void gemm_mainloop(const u16* Ag, const u16* Bg,
                                              u16* As, u16* Bs,
                                              f32x4 acc[4][4], int tid) {
  const int lane = tid & 63;
  const int wr = tid >> 7, wc = (tid >> 6) & 1;  // 4 waves in 2x2, wave tile 64x64
  for (int k0 = 0; k0 < 2048; k0 += 64) {
    __syncthreads();  // previous iter's reads done before overwrite
#pragma unroll
    for (int it = 0; it < 4; ++it) {
      int s = it * 256 + tid;
      int pb = s * 16;                           // physical (linear) LDS byte
      int lb = pb ^ ((((pb) >> 7) & 7) << 4);    // logical byte (involution)
      int row = lb >> 7;                         // 0..127
      int k8 = (lb >> 4) & 7;                    // 16B granule within row
      const u16* ga = Ag + (size_t)row * 2048 + k0 + k8 * 8;
      const u16* gb = Bg + (size_t)row * 2048 + k0 + k8 * 8;
      char* la = (char*)As + it * 4096 + (tid & 192) * 16;  // wave-uniform base
      char* lb2 = (char*)Bs + it * 4096 + (tid & 192) * 16;
      __builtin_amdgcn_global_load_lds((gvoid*)(void*)ga, (svoid*)la, 16, 0, 0);
      __builtin_amdgcn_global_load_lds((gvoid*)(void*)gb, (svoid*)lb2, 16, 0, 0);
    }
    __syncthreads();
#pragma unroll
    for (int ks = 0; ks < 2; ++ks) {
      B8 a[4], b[4];
#pragma unroll
      for (int i = 0; i < 4; ++i) {
        int rowa = wr * 64 + i * 16 + (lane & 15);
        int ba = rowa * 128 + ks * 64 + (lane >> 4) * 16;
        ba ^= (rowa & 7) << 4;
        a[i].u = *(const uint4*)((const char*)As + ba);
        int rowb = wc * 64 + i * 16 + (lane & 15);
        int bb = rowb * 128 + ks * 64 + (lane >> 4) * 16;
        bb ^= (rowb & 7) << 4;
        b[i].u = *(const uint4*)((const char*)Bs + bb);
      }
#pragma unroll
      for (int i = 0; i < 4; ++i)
#pragma unroll
        for (int j = 0; j < 4; ++j)
          acc[i][j] = __builtin_amdgcn_mfma_f32_16x16x32_bf16(a[i].b, b[j].b, acc[i][j], 0, 0, 0);
    }
  }
}

// ---------------- fused QKV projection ----------------
// grid (16 m-tiles, 48 col-tiles): col-tile = one (tensor tau, head) pair.
__global__ __launch_bounds__(256) void qkv_gemm_kernel(const u16* __restrict__ Xb,
                                                       const u16* __restrict__ Wb,
                                                       u16* __restrict__ Qb,
                                                       u16* __restrict__ Kb,
                                                       u16* __restrict__ VTb) {
  __shared__ __align__(16) u16 As[128 * 64];
  __shared__ __align__(16) u16 Bs[128 * 64];
  int tid = threadIdx.x;
  int m0 = blockIdx.x * 128;
  int c0 = blockIdx.y;           // 0..47
  int tau = c0 >> 4, head = c0 & 15;
  f32x4 z = {0.f, 0.f, 0.f, 0.f};
  f32x4 acc[4][4];
#pragma unroll
  for (int i = 0; i < 4; ++i)
#pragma unroll
    for (int j = 0; j < 4; ++j) acc[i][j] = z;
  gemm_mainloop(Xb + (size_t)m0 * 2048, Wb + (size_t)c0 * 128 * 2048, As, Bs, acc, tid);

  int lane = tid & 63, wr = tid >> 7, wc = (tid >> 6) & 1;
  if (tau < 2) {
    u16* Oh = ((tau == 0) ? Qb : Kb) + (size_t)head * 2048 * 128;
    float sc = (tau == 0) ? 0.08838834764831845f : 1.0f;  // fold 1/sqrt(128) into Q
#pragma unroll
    for (int i = 0; i < 4; ++i) {
      int rb = m0 + wr * 64 + i * 16 + (lane >> 4) * 4;  // C layout: row=(l>>4)*4+r
#pragma unroll
      for (int j = 0; j < 4; ++j) {
        int col = wc * 64 + j * 16 + (lane & 15);        // C layout: col=l&15
#pragma unroll
        for (int r = 0; r < 4; ++r)
          Oh[(size_t)(rb + r) * 128 + col] = f2b(acc[i][j][r] * sc);
      }
    }
  } else {  // V: store transposed (h, t) so PV B-operand is k-contiguous
    u16* Vh = VTb + (size_t)head * 128 * 2048;
#pragma unroll
    for (int i = 0; i < 4; ++i) {
      int rb = m0 + wr * 64 + i * 16 + (lane >> 4) * 4;
#pragma unroll
      for (int j = 0; j < 4; ++j) {
        int col = wc * 64 + j * 16 + (lane & 15);
        ushort4 v;
        v.x = f2b(acc[i][j][0]); v.y = f2b(acc[i][j][1]);
        v.z = f2b(acc[i][j][2]); v.w = f2b(acc[i][j][3]);
        *(ushort4*)(Vh + (size_t)col * 2048 + rb) = v;   // 4 consecutive t -> 8B store
      }
    }
  }
}

// ---------------- flash attention ----------------
// grid (32 q-tiles of 64 rows, 16 heads), 256 thr = 4 waves, wave owns 16 q-rows.
// KV tile = 64. K staged [64][136] (pad -> 2-way banks), V^T staged [128][72], P [16][72]/wave.
__global__ __launch_bounds__(256) void attn_kernel(const u16* __restrict__ Qb,
                                                   const u16* __restrict__ Kb,
                                                   const u16* __restrict__ VTb,
                                                   u16* __restrict__ Rb) {
  __shared__ __align__(16) u16 Ks[64 * 136];
  __shared__ __align__(16) u16 Vs[128 * 72];
  __shared__ __align__(16) u16 Ps[4 * 16 * 72];
  int tid = threadIdx.x, lane = tid & 63, w = tid >> 6;
  int q0 = blockIdx.x * 64, head = blockIdx.y;
  const u16* Qh = Qb + (size_t)head * 2048 * 128;
  const u16* Kh = Kb + (size_t)head * 2048 * 128;
  const u16* Vh = VTb + (size_t)head * 128 * 2048;

  // Q fragments held in registers for the whole kernel (A layout: row=l&15, k contig)
  B8 q[4];
  {
    int qrow = q0 + w * 16 + (lane & 15);
#pragma unroll
    for (int ks = 0; ks < 4; ++ks)
      q[ks].u = *(const uint4*)(Qh + (size_t)qrow * 128 + ks * 32 + (lane >> 4) * 8);
  }

  f32x4 o[8];
  f32x4 z4 = {0.f, 0.f, 0.f, 0.f};
#pragma unroll
  for (int f = 0; f < 8; ++f) o[f] = z4;
  float m_run[4] = {-1e30f, -1e30f, -1e30f, -1e30f};
  float l_run[4] = {0.f, 0.f, 0.f, 0.f};

  for (int s0 = 0; s0 < 2048; s0 += 64) {
    __syncthreads();
    // stage K tile (64 x 128) reg->LDS, padded stride 136
#pragma unroll
    for (int p = 0; p < 4; ++p) {
      int r = p * 16 + (tid >> 4), cb = tid & 15;
      *(uint4*)(Ks + r * 136 + cb * 8) =
          *(const uint4*)(Kh + (size_t)(s0 + r) * 128 + cb * 8);
    }
    // stage V^T tile (128 x 64), padded stride 72
#pragma unroll
    for (int p = 0; p < 4; ++p) {
      int r = p * 32 + (tid >> 3), cb = tid & 7;
      *(uint4*)(Vs + r * 72 + cb * 8) =
          *(const uint4*)(Vh + (size_t)r * 2048 + s0 + cb * 8);
    }
    __syncthreads();

    // S = Q K^T (pre-scaled): 16 MFMA/wave
    f32x4 s[4];
#pragma unroll
    for (int f = 0; f < 4; ++f) s[f] = z4;
#pragma unroll
    for (int f = 0; f < 4; ++f)
#pragma unroll
      for (int ks = 0; ks < 4; ++ks) {
        B8 kb;
        kb.u = *(const uint4*)(Ks + (f * 16 + (lane & 15)) * 136 + ks * 32 + (lane >> 4) * 8);
        s[f] = __builtin_amdgcn_mfma_f32_16x16x32_bf16(q[ks].b, kb.b, s[f], 0, 0, 0);
      }

    // online softmax over this tile's 64 cols; lane's 4 rows = (l>>4)*4+i
    float mt[4];
#pragma unroll
    for (int i = 0; i < 4; ++i)
      mt[i] = fmaxf(fmaxf(s[0][i], s[1][i]), fmaxf(s[2][i], s[3][i]));
#pragma unroll
    for (int mask = 1; mask <= 8; mask <<= 1)
#pragma unroll
      for (int i = 0; i < 4; ++i) mt[i] = fmaxf(mt[i], __shfl_xor(mt[i], mask, 64));

    float al[4];
#pragma unroll
    for (int i = 0; i < 4; ++i) {
      float mn = fmaxf(m_run[i], mt[i]);
      al[i] = __expf(m_run[i] - mn);
      m_run[i] = mn;
    }
    u16* Pw = Ps + w * 16 * 72;
    float ps[4] = {0.f, 0.f, 0.f, 0.f};
#pragma unroll
    for (int f = 0; f < 4; ++f)
#pragma unroll
      for (int i = 0; i < 4; ++i) {
        float p = __expf(s[f][i] - m_run[i]);
        ps[i] += p;
        Pw[((lane >> 4) * 4 + i) * 72 + f * 16 + (lane & 15)] = f2b(p);
      }
#pragma unroll
    for (int mask = 1; mask <= 8; mask <<= 1)
#pragma unroll
      for (int i = 0; i < 4; ++i) ps[i] += __shfl_xor(ps[i], mask, 64);
#pragma unroll
    for (int i = 0; i < 4; ++i) l_run[i] = l_run[i] * al[i] + ps[i];

    // rescale O then accumulate P*V (16 MFMA/wave)
#pragma unroll
    for (int f = 0; f < 8; ++f)
#pragma unroll
      for (int i = 0; i < 4; ++i) o[f][i] *= al[i];

    B8 pa[2];
#pragma unroll
    for (int k2 = 0; k2 < 2; ++k2)
      pa[k2].u = *(const uint4*)(Pw + (lane & 15) * 72 + k2 * 32 + (lane >> 4) * 8);
#pragma unroll
    for (int f = 0; f < 8; ++f)
#pragma unroll
      for (int k2 = 0; k2 < 2; ++k2) {
        B8 vb;
        vb.u = *(const uint4*)(Vs + (f * 16 + (lane & 15)) * 72 + k2 * 32 + (lane >> 4) * 8);
        o[f] = __builtin_amdgcn_mfma_f32_16x16x32_bf16(pa[k2].b, vb.b, o[f], 0, 0, 0);
      }
  }

  // normalize and write R in (t, n*128+h) layout
#pragma unroll
  for (int i = 0; i < 4; ++i) {
    float inv = 1.0f / l_run[i];
    int row = q0 + w * 16 + (lane >> 4) * 4 + i;
#pragma unroll
    for (int f = 0; f < 8; ++f) {
      int col = head * 128 + f * 16 + (lane & 15);
      Rb[(size_t)row * 2048 + col] = f2b(o[f][i] * inv);
    }
  }
}

// ---------------- output projection: out = R(2048x2048) * W_out ----------------
__global__ __launch_bounds__(256) void out_gemm_kernel(const u16* __restrict__ Rb,
                                                       const u16* __restrict__ Wob,
                                                       float* __restrict__ out) {
  __shared__ __align__(16) u16 As[128 * 64];
  __shared__ __align__(16) u16 Bs[128 * 64];
  int tid = threadIdx.x;
  int m0 = blockIdx.x * 128, n0 = blockIdx.y * 128;
  f32x4 z = {0.f, 0.f, 0.f, 0.f};
  f32x4 acc[4][4];
#pragma unroll
  for (int i = 0; i < 4; ++i)
#pragma unroll
    for (int j = 0; j < 4; ++j) acc[i][j] = z;
  gemm_mainloop(Rb + (size_t)m0 * 2048, Wob + (size_t)n0 * 2048, As, Bs, acc, tid);

  int lane = tid & 63, wr = tid >> 7, wc = (tid >> 6) & 1;
#pragma unroll
  for (int i = 0; i < 4; ++i) {
    int rb = m0 + wr * 64 + i * 16 + (lane >> 4) * 4;
#pragma unroll
    for (int j = 0; j < 4; ++j) {
      int col = n0 + wc * 64 + j * 16 + (lane & 15);
#pragma unroll
      for (int r = 0; r < 4; ++r)
        out[(size_t)(rb + r) * 2048 + col] = acc[i][j][r];
    }
  }
}

extern "C" void kernel_launch(void* const* d_in, const int* in_sizes, int n_in,
                              void* d_out, int out_size, void* d_ws, size_t ws_size,
                              hipStream_t stream) {
  const float* X  = (const float*)d_in[0];
  const float* WQ = (const float*)d_in[1];
  const float* WK = (const float*)d_in[2];
  const float* WV = (const float*)d_in[3];
  const float* WO = (const float*)d_in[4];
  float* out = (float*)d_out;

  char* ws = (char*)d_ws;
  const size_t MB8 = 8u << 20;
  u16* Xb    = (u16*)(ws);
  u16* Wqkvb = (u16*)(ws + MB8);          // 3 x 8 MiB
  u16* Woutb = (u16*)(ws + 4 * MB8);
  u16* Qb    = (u16*)(ws + 5 * MB8);
  u16* Kb    = (u16*)(ws + 6 * MB8);
  u16* VTb   = (u16*)(ws + 7 * MB8);
  u16* Rbuf  = (u16*)(ws + MB8);          // aliases Wqkvb[W_Q]: dead after qkv_gemm

  cvt_x_kernel<<<dim3(4096), dim3(256), 0, stream>>>(X, Xb);
  tcvt_kernel<<<dim3(4, 64, 16), dim3(32, 8), 0, stream>>>(WQ, Wqkvb, 2048, 128);
  tcvt_kernel<<<dim3(4, 64, 16), dim3(32, 8), 0, stream>>>(WK, Wqkvb + (size_t)16 * 128 * 2048, 2048, 128);
  tcvt_kernel<<<dim3(4, 64, 16), dim3(32, 8), 0, stream>>>(WV, Wqkvb + (size_t)32 * 128 * 2048, 2048, 128);
  tcvt_kernel<<<dim3(64, 64, 1), dim3(32, 8), 0, stream>>>(WO, Woutb, 2048, 2048);

  qkv_gemm_kernel<<<dim3(16, 48), dim3(256), 0, stream>>>(Xb, Wqkvb, Qb, Kb, VTb);
  attn_kernel<<<dim3(32, 16), dim3(256), 0, stream>>>(Qb, Kb, VTb, Rbuf);
  out_gemm_kernel<<<dim3(16, 16), dim3(256), 0, stream>>>(Rbuf, Woutb, out);
}